// Round 3
// baseline (370.640 us; speedup 1.0000x reference)
//
#include <hip/hip_runtime.h>

constexpr int Bv  = 8;
constexpr int NQ  = 512;
constexpr int NKV = 512;
constexpr int Hh  = 16;
constexpr int Dd  = 256;

// Seed proj with b_in and out with b_out (both get atomicAdd'ed by the
// K-split GEMMs). Also fixes the harness's 0xAA poison.
__global__ __launch_bounds__(256) void init_bias(
    float* __restrict__ proj, float* __restrict__ out,
    const float* __restrict__ b_in, const float* __restrict__ b_out) {
  const int i = blockIdx.x * 256 + threadIdx.x;   // 262144 float4 slots each
  const float4 bi = ((const float4*)b_in)[i & 63];
  const float4 bo = ((const float4*)b_out)[i & 63];
  ((float4*)proj)[i] = bi;
  ((float4*)out)[i]  = bo;
}

// C[m][n] += sum_{k in block's K-slice} A[m][k]*W[n][k]
// 64x64 tile, 4x4/thread, K split 4 ways over gridDim.z -> 1024 blocks
// (4 blocks/CU, 16 waves/CU). Epilogue: hardware fp32 atomics.
__global__ __launch_bounds__(256) void gemm_abt_atomic(
    const float* __restrict__ A, const float* __restrict__ W,
    float* __restrict__ C) {
  __shared__ float As[16][68];
  __shared__ float Ws[16][68];
  const int t  = threadIdx.x;
  const int tx = t & 15;
  const int ty = t >> 4;
  const int m0 = blockIdx.x * 64;
  const int n0 = blockIdx.y * 64;
  const int kb = blockIdx.z * 64;   // this block's K-slice [kb, kb+64)
  const int lr = t >> 2;
  const int lk = (t & 3) << 2;

  float acc[4][4] = {};

  for (int kt = 0; kt < 4; ++kt) {
    const int k0 = kb + kt * 16;
    __syncthreads();
    const float4 av = *(const float4*)(A + (size_t)(m0 + lr) * 256 + k0 + lk);
    const float4 wv = *(const float4*)(W + (size_t)(n0 + lr) * 256 + k0 + lk);
    As[lk + 0][lr] = av.x; As[lk + 1][lr] = av.y;
    As[lk + 2][lr] = av.z; As[lk + 3][lr] = av.w;
    Ws[lk + 0][lr] = wv.x; Ws[lk + 1][lr] = wv.y;
    Ws[lk + 2][lr] = wv.z; Ws[lk + 3][lr] = wv.w;
    __syncthreads();
#pragma unroll
    for (int k = 0; k < 16; ++k) {
      float a_[4], w_[4];
      *(float4*)a_ = *(const float4*)&As[k][ty << 2];
      *(float4*)w_ = *(const float4*)&Ws[k][tx << 2];
#pragma unroll
      for (int i = 0; i < 4; ++i)
#pragma unroll
        for (int j = 0; j < 4; ++j)
          acc[i][j] = fmaf(a_[i], w_[j], acc[i][j]);
    }
  }

#pragma unroll
  for (int i = 0; i < 4; ++i)
#pragma unroll
    for (int j = 0; j < 4; ++j)
      unsafeAtomicAdd(C + (size_t)(m0 + (ty << 2) + i) * 256 + n0 + (tx << 2) + j,
                      acc[i][j]);
}

// Fused masked softmax + per-head aggregation + L2 rescale.
// Grid 512 x 256 threads. Thread: 2 q-rows, dcol = lane*4 (wave reads 1KB
// contiguous LDS -> conflict-free b128, each read feeds 8 FMAs).
// Explicit 2-slot software pipeline on adj/msg global loads.
__global__ __launch_bounds__(256) void attn_kernel(
    const float* __restrict__ msg, const int* __restrict__ adj,
    const float* __restrict__ proj, float* __restrict__ attn_out) {
  __shared__ float Psh[32 * Dd];  // 32 KB

  const int t    = threadIdx.x;
  const int lane = t & 63;
  const int dcol = lane << 2;     // contiguous within wave
  const int h    = lane >> 2;
  const int wq   = t >> 6;        // 0..3
  const int b    = blockIdx.x >> 6;
  const int q0   = (blockIdx.x & 63) * 8 + wq * 2;

  const float* mp0 = msg + ((size_t)(b * NQ + q0) * NKV) * Hh + h;
  const float* mp1 = mp0 + (size_t)NKV * Hh;
  const int*   ap0 = adj + (size_t)(b * NQ + q0) * NKV;
  const int*   ap1 = ap0 + NKV;
  const float* pb  = proj + (size_t)b * NKV * Dd;

  float o0[4] = {}, o1[4] = {};
  float s0 = 0.f, s1 = 0.f, r0 = 0.f, r1 = 0.f;

  for (int k0 = 0; k0 < NKV; k0 += 32) {
    __syncthreads();
    {  // stage proj[b, k0:k0+32, :] -> LDS, coalesced float4
      const float4* src = (const float4*)(pb + (size_t)k0 * Dd);
      float4* dst = (float4*)Psh;
#pragma unroll
      for (int i = 0; i < 8; ++i) dst[t + i * 256] = src[t + i * 256];
    }
    __syncthreads();

    // 8 groups of 4 k, 2-slot pipeline on global loads
    int   a0v[2][4], a1v[2][4];
    float m0v[2][4], m1v[2][4];
    {  // preload group 0
      *(int4*)a0v[0] = *(const int4*)(ap0 + k0);
      *(int4*)a1v[0] = *(const int4*)(ap1 + k0);
#pragma unroll
      for (int j = 0; j < 4; ++j) {
        m0v[0][j] = mp0[(size_t)(k0 + j) * Hh];
        m1v[0][j] = mp1[(size_t)(k0 + j) * Hh];
      }
    }
#pragma unroll
    for (int g = 0; g < 8; ++g) {
      const int cur = g & 1, nxt = cur ^ 1;
      if (g < 7) {  // issue loads for group g+1; consumed next iteration
        const int kk = k0 + (g + 1) * 4;
        *(int4*)a0v[nxt] = *(const int4*)(ap0 + kk);
        *(int4*)a1v[nxt] = *(const int4*)(ap1 + kk);
#pragma unroll
        for (int j = 0; j < 4; ++j) {
          m0v[nxt][j] = mp0[(size_t)(kk + j) * Hh];
          m1v[nxt][j] = mp1[(size_t)(kk + j) * Hh];
        }
      }
#pragma unroll
      for (int j = 0; j < 4; ++j) {
        const float e0 = (a0v[cur][j] > 0) ? __expf(m0v[cur][j]) : 0.0f;
        const float e1 = (a1v[cur][j] > 0) ? __expf(m1v[cur][j]) : 0.0f;
        s0 += e0; r0 = fmaf(e0, e0, r0);
        s1 += e1; r1 = fmaf(e1, e1, r1);
        float p[4];
        *(float4*)p = *(const float4*)(Psh + (g * 4 + j) * Dd + dcol);
#pragma unroll
        for (int d = 0; d < 4; ++d) {
          o0[d] = fmaf(e0, p[d], o0[d]);
          o1[d] = fmaf(e1, p[d], o1[d]);
        }
      }
    }
  }

  const float w0 = sqrtf(r0) / (s0 * s0);
  const float w1 = sqrtf(r1) / (s1 * s1);
  float4 u0, u1;
  u0.x = o0[0] * w0; u0.y = o0[1] * w0; u0.z = o0[2] * w0; u0.w = o0[3] * w0;
  u1.x = o1[0] * w1; u1.y = o1[1] * w1; u1.z = o1[2] * w1; u1.w = o1[3] * w1;
  *(float4*)(attn_out + (size_t)(b * NQ + q0) * Dd + dcol)     = u0;
  *(float4*)(attn_out + (size_t)(b * NQ + q0 + 1) * Dd + dcol) = u1;
}

extern "C" void kernel_launch(void* const* d_in, const int* in_sizes, int n_in,
                              void* d_out, int out_size, void* d_ws, size_t ws_size,
                              hipStream_t stream) {
  const float* v_inv    = (const float*)d_in[0];
  const float* messages = (const float*)d_in[1];
  const int*   adj      = (const int*)d_in[2];
  const float* W_in     = (const float*)d_in[3];
  const float* b_in     = (const float*)d_in[4];
  const float* W_out    = (const float*)d_in[5];
  const float* b_out    = (const float*)d_in[6];
  float* out = (float*)d_out;

  float* proj = (float*)d_ws;                    // 4 MB [B,NKV,D]
  float* attn = proj + (size_t)Bv * NKV * Dd;    // 4 MB [B,NQ,D]

  init_bias<<<1024, 256, 0, stream>>>(proj, out, b_in, b_out);
  dim3 gemm_grid(4096 / 64, 256 / 64, 4);
  gemm_abt_atomic<<<gemm_grid, 256, 0, stream>>>(v_inv, W_in, proj);
  attn_kernel<<<512, 256, 0, stream>>>(messages, adj, proj, attn);
  gemm_abt_atomic<<<gemm_grid, 256, 0, stream>>>(attn, W_out, out);
}

// Round 4
// 355.301 us; speedup vs baseline: 1.0432x; 1.0432x over previous
//
#include <hip/hip_runtime.h>

constexpr int Bv  = 8;
constexpr int NQ  = 512;
constexpr int NKV = 512;
constexpr int Hh  = 16;
constexpr int Dd  = 256;

// ws layout (float offsets). Lifetimes:
//  gemm1 partials -> [ATTN, BUF8]; gemm1red -> PROJ; attn partials -> d_out + BUF8 (+S/R);
//  attnred -> ATTN; gemm2 partials -> [PROJ, BUF8]; gemm2red -> d_out.
constexpr size_t OFF_PROJ = 0;
constexpr size_t OFF_ATTN = (size_t)1 << 20;   // 4 MB
constexpr size_t OFF_BUF8 = (size_t)2 << 20;   // 4 MB
constexpr size_t OFF_SA   = (size_t)3 << 20;
constexpr size_t OFF_RA   = OFF_SA + 65536;
constexpr size_t OFF_SB   = OFF_SA + 131072;
constexpr size_t OFF_RB   = OFF_SA + 196608;

// Partial GEMM: Cp[m][n] = sum_{k in 128-slice} A[m][k]*W[n][k]. M=4096,N=256.
// 64x64 tile, 4x4/thread, BK=64 (4 barriers/block). grid (64,4,2) = 512 blocks.
__global__ __launch_bounds__(256) void gemm_abt_part(
    const float* __restrict__ A, const float* __restrict__ W,
    float* __restrict__ Cp0, float* __restrict__ Cp1) {
  __shared__ float As[64][68];
  __shared__ float Ws[64][68];
  const int t  = threadIdx.x;
  const int tx = t & 15, ty = t >> 4;
  const int m0 = blockIdx.x * 64, n0 = blockIdx.y * 64;
  const int ks = blockIdx.z * 128;

  float acc[4][4] = {};

  for (int tile = 0; tile < 2; ++tile) {
    const int kb = ks + tile * 64;
    __syncthreads();
#pragma unroll
    for (int i = 0; i < 4; ++i) {
      const int flat = i * 256 + t;
      const int r = flat >> 4, c4 = (flat & 15) << 2;
      const float4 av = *(const float4*)(A + (size_t)(m0 + r) * 256 + kb + c4);
      const float4 wv = *(const float4*)(W + (size_t)(n0 + r) * 256 + kb + c4);
      As[c4 + 0][r] = av.x; As[c4 + 1][r] = av.y;
      As[c4 + 2][r] = av.z; As[c4 + 3][r] = av.w;
      Ws[c4 + 0][r] = wv.x; Ws[c4 + 1][r] = wv.y;
      Ws[c4 + 2][r] = wv.z; Ws[c4 + 3][r] = wv.w;
    }
    __syncthreads();
#pragma unroll 16
    for (int k = 0; k < 64; ++k) {
      float a_[4], w_[4];
      *(float4*)a_ = *(const float4*)&As[k][ty << 2];
      *(float4*)w_ = *(const float4*)&Ws[k][tx << 2];
#pragma unroll
      for (int i = 0; i < 4; ++i)
#pragma unroll
        for (int j = 0; j < 4; ++j)
          acc[i][j] = fmaf(a_[i], w_[j], acc[i][j]);
    }
  }

  float* Cp = blockIdx.z ? Cp1 : Cp0;
#pragma unroll
  for (int i = 0; i < 4; ++i) {
    float4 cv = {acc[i][0], acc[i][1], acc[i][2], acc[i][3]};
    *(float4*)(Cp + (size_t)(m0 + (ty << 2) + i) * 256 + n0 + (tx << 2)) = cv;
  }
}

// dst = p0 + p1 + bias (bias broadcast over 256-col rows). 1M floats.
__global__ __launch_bounds__(256) void add2_bias(
    const float4* __restrict__ p0, const float4* __restrict__ p1,
    const float* __restrict__ bias, float4* __restrict__ dst) {
  const int i = blockIdx.x * 256 + threadIdx.x;
  const float4 a = p0[i], b = p1[i];
  const float4 bb = ((const float4*)bias)[i & 63];
  float4 o;
  o.x = a.x + b.x + bb.x; o.y = a.y + b.y + bb.y;
  o.z = a.z + b.z + bb.z; o.w = a.w + b.w + bb.w;
  dst[i] = o;
}

// attn partial: grid (64 qc, 8 b, 2 k-half), 256 thr. Wave owns 2 q-rows over
// a 256-k slice. lane = (k4 = lane>>4, h = lane&15): msg loads coalesced
// (64 consecutive floats / wave instr), exp computed once per (q,k,h).
// proj staged in LDS, row stride 65 float4 -> uniform bank quads.
// Emits raw partial sums (o, s=sum e, r=sum e^2); reduce kernel finishes.
__global__ __launch_bounds__(256) void attn_part(
    const float* __restrict__ msg, const int* __restrict__ adj,
    const float* __restrict__ proj,
    float* __restrict__ oA, float* __restrict__ oB,
    float* __restrict__ sA, float* __restrict__ rA,
    float* __restrict__ sB, float* __restrict__ rB) {
  __shared__ float4 Psh[32 * 65];  // 33280 B

  const int t    = threadIdx.x;
  const int lane = t & 63;
  const int k4   = lane >> 4;
  const int h    = lane & 15;
  const int wq   = t >> 6;
  const int qc   = blockIdx.x;
  const int b    = blockIdx.y;
  const int ks   = blockIdx.z;
  const int q0   = qc * 8 + wq * 2;
  const int kbase = ks * 256;

  const float* mp0 = msg + (size_t)(b * NQ + q0) * NKV * Hh;
  const float* mp1 = mp0 + (size_t)NKV * Hh;
  const int*   ap0 = adj + (size_t)(b * NQ + q0) * NKV;
  const int*   ap1 = ap0 + NKV;
  const float4* pb4 = (const float4*)(proj + (size_t)b * NKV * Dd);

  float4 o0[4] = {}, o1[4] = {};
  float s0 = 0.f, s1 = 0.f, r0 = 0.f, r1 = 0.f;

  for (int tile = 0; tile < 8; ++tile) {
    const int kt = kbase + tile * 32;
    __syncthreads();
#pragma unroll
    for (int i = 0; i < 8; ++i) {  // stage 32 k-rows x 64 float4
      const int flat = i * 256 + t;
      const int kk = flat >> 6, c4 = flat & 63;
      Psh[kk * 65 + c4] = pb4[(size_t)(kt + kk) * 64 + c4];
    }
    __syncthreads();
#pragma unroll
    for (int g = 0; g < 8; ++g) {
      const int kl = g * 4 + k4;   // local k (this lane's)
      const int gk = kt + kl;      // global k
      const float m0v = mp0[(size_t)gk * Hh + h];
      const float m1v = mp1[(size_t)gk * Hh + h];
      const float e0 = (ap0[gk] > 0) ? __expf(m0v) : 0.f;
      const float e1 = (ap1[gk] > 0) ? __expf(m1v) : 0.f;
      s0 += e0; r0 = fmaf(e0, e0, r0);
      s1 += e1; r1 = fmaf(e1, e1, r1);
#pragma unroll
      for (int j = 0; j < 4; ++j) {
        const float4 p = Psh[kl * 65 + (h << 2) + j];
        o0[j].x = fmaf(e0, p.x, o0[j].x); o0[j].y = fmaf(e0, p.y, o0[j].y);
        o0[j].z = fmaf(e0, p.z, o0[j].z); o0[j].w = fmaf(e0, p.w, o0[j].w);
        o1[j].x = fmaf(e1, p.x, o1[j].x); o1[j].y = fmaf(e1, p.y, o1[j].y);
        o1[j].z = fmaf(e1, p.z, o1[j].z); o1[j].w = fmaf(e1, p.w, o1[j].w);
      }
    }
  }

  // butterfly-reduce over k4 (lanes xor 16, 32); h preserved
  float* o0f = (float*)o0;
  float* o1f = (float*)o1;
#pragma unroll
  for (int d = 0; d < 16; ++d) {
    o0f[d] += __shfl_xor(o0f[d], 16); o0f[d] += __shfl_xor(o0f[d], 32);
    o1f[d] += __shfl_xor(o1f[d], 16); o1f[d] += __shfl_xor(o1f[d], 32);
  }
  s0 += __shfl_xor(s0, 16); s0 += __shfl_xor(s0, 32);
  s1 += __shfl_xor(s1, 16); s1 += __shfl_xor(s1, 32);
  r0 += __shfl_xor(r0, 16); r0 += __shfl_xor(r0, 32);
  r1 += __shfl_xor(r1, 16); r1 += __shfl_xor(r1, 32);

  float* oP = ks ? oB : oA;
  float* sP = ks ? sB : sA;
  float* rP = ks ? rB : rA;
  if (lane < 16) {
    const int hh = lane;  // == h for these lanes
    float4* d0 = (float4*)(oP + (size_t)(b * NQ + q0) * Dd + hh * 16);
    float4* d1 = (float4*)(oP + (size_t)(b * NQ + q0 + 1) * Dd + hh * 16);
#pragma unroll
    for (int j = 0; j < 4; ++j) { d0[j] = o0[j]; d1[j] = o1[j]; }
    sP[(size_t)(b * NQ + q0) * Hh + hh] = s0;
    sP[(size_t)(b * NQ + q0 + 1) * Hh + hh] = s1;
    rP[(size_t)(b * NQ + q0) * Hh + hh] = r0;
    rP[(size_t)(b * NQ + q0 + 1) * Hh + hh] = r1;
  }
}

// attn[b,q,d] = (oA+oB) * sqrt(rA+rB) / (sA+sB)^2
__global__ __launch_bounds__(256) void attn_reduce(
    const float4* __restrict__ oA4, const float4* __restrict__ oB4,
    const float* __restrict__ sA, const float* __restrict__ rA,
    const float* __restrict__ sB, const float* __restrict__ rB,
    float4* __restrict__ attn4) {
  const int i  = blockIdx.x * 256 + threadIdx.x;  // float4 index
  const int qg = i >> 6;                          // b*NQ + q
  const int hh = (i & 63) >> 2;
  const float s = sA[qg * 16 + hh] + sB[qg * 16 + hh];
  const float r = rA[qg * 16 + hh] + rB[qg * 16 + hh];
  const float w = sqrtf(r) / (s * s);
  const float4 a = oA4[i], b = oB4[i];
  float4 o;
  o.x = (a.x + b.x) * w; o.y = (a.y + b.y) * w;
  o.z = (a.z + b.z) * w; o.w = (a.w + b.w) * w;
  attn4[i] = o;
}

extern "C" void kernel_launch(void* const* d_in, const int* in_sizes, int n_in,
                              void* d_out, int out_size, void* d_ws, size_t ws_size,
                              hipStream_t stream) {
  const float* v_inv    = (const float*)d_in[0];
  const float* messages = (const float*)d_in[1];
  const int*   adj      = (const int*)d_in[2];
  const float* W_in     = (const float*)d_in[3];
  const float* b_in     = (const float*)d_in[4];
  const float* W_out    = (const float*)d_in[5];
  const float* b_out    = (const float*)d_in[6];
  float* out = (float*)d_out;
  float* ws  = (float*)d_ws;

  float* proj = ws + OFF_PROJ;
  float* attn = ws + OFF_ATTN;
  float* buf8 = ws + OFF_BUF8;
  float* sA = ws + OFF_SA; float* rA = ws + OFF_RA;
  float* sB = ws + OFF_SB; float* rB = ws + OFF_RB;

  dim3 gg(64, 4, 2);
  // proj = v_inv @ W_in^T + b_in   (partials in attn/buf8 regions)
  gemm_abt_part<<<gg, 256, 0, stream>>>(v_inv, W_in, attn, buf8);
  add2_bias<<<1024, 256, 0, stream>>>((const float4*)attn, (const float4*)buf8,
                                      b_in, (float4*)proj);
  // fused masked softmax + aggregation, k-split 2 (partial A in d_out)
  attn_part<<<dim3(64, 8, 2), 256, 0, stream>>>(messages, adj, proj,
                                                out, buf8, sA, rA, sB, rB);
  attn_reduce<<<1024, 256, 0, stream>>>((const float4*)out, (const float4*)buf8,
                                        sA, rA, sB, rB, (float4*)attn);
  // out = attn @ W_out^T + b_out   (partials in proj/buf8 regions)
  gemm_abt_part<<<gg, 256, 0, stream>>>(attn, W_out, proj, buf8);
  add2_bias<<<1024, 256, 0, stream>>>((const float4*)proj, (const float4*)buf8,
                                      b_out, (float4*)out);
}

// Round 5
// 324.432 us; speedup vs baseline: 1.1424x; 1.0951x over previous
//
#include <hip/hip_runtime.h>

constexpr int NQ = 512;
constexpr int NKV = 512;
constexpr int Hh = 16;
constexpr int Dd = 256;

// C = A @ W^T + bias. M=4096, N=256, K=256. BM=BN=64, BK=64 (4 tiles).
// Grid (64,4) = 256 blocks. K-major LDS (stride 68), 4x4 acc/thread.
__global__ __launch_bounds__(256) void gemm_bias(
    const float* __restrict__ A, const float* __restrict__ W,
    const float* __restrict__ bias, float* __restrict__ C) {
  __shared__ float As[64][68];
  __shared__ float Ws[64][68];
  const int t = threadIdx.x;
  const int tx = t & 15, ty = t >> 4;
  const int m0 = blockIdx.x * 64, n0 = blockIdx.y * 64;

  float acc[4][4] = {};

  for (int kb = 0; kb < 256; kb += 64) {
    __syncthreads();
#pragma unroll
    for (int i = 0; i < 4; ++i) {
      const int flat = i * 256 + t;
      const int r = flat >> 4, c4 = (flat & 15) << 2;
      const float4 av = *(const float4*)(A + (size_t)(m0 + r) * 256 + kb + c4);
      const float4 wv = *(const float4*)(W + (size_t)(n0 + r) * 256 + kb + c4);
      As[c4 + 0][r] = av.x; As[c4 + 1][r] = av.y;
      As[c4 + 2][r] = av.z; As[c4 + 3][r] = av.w;
      Ws[c4 + 0][r] = wv.x; Ws[c4 + 1][r] = wv.y;
      Ws[c4 + 2][r] = wv.z; Ws[c4 + 3][r] = wv.w;
    }
    __syncthreads();
#pragma unroll 16
    for (int k = 0; k < 64; ++k) {
      float a_[4], w_[4];
      *(float4*)a_ = *(const float4*)&As[k][ty << 2];
      *(float4*)w_ = *(const float4*)&Ws[k][tx << 2];
#pragma unroll
      for (int i = 0; i < 4; ++i)
#pragma unroll
        for (int j = 0; j < 4; ++j)
          acc[i][j] = fmaf(a_[i], w_[j], acc[i][j]);
    }
  }

  const float4 bv = *(const float4*)(bias + n0 + (tx << 2));
  const float bb[4] = {bv.x, bv.y, bv.z, bv.w};
#pragma unroll
  for (int i = 0; i < 4; ++i) {
    float4 cv;
    cv.x = acc[i][0] + bb[0]; cv.y = acc[i][1] + bb[1];
    cv.z = acc[i][2] + bb[2]; cv.w = acc[i][3] + bb[3];
    *(float4*)(C + (size_t)(m0 + (ty << 2) + i) * 256 + n0 + (tx << 2)) = cv;
  }
}

// Fused masked softmax + per-head aggregation + L2 rescale.
// Grid (32 qc, 8 b) x 512 thr. Intra-block k-split: waves 0-3 do k[0,256),
// waves 4-7 do k[256,512); same 16 q-rows. Thread = 4 q x 4 d, dcol = lane*4
// (wave LDS reads = 1KB contiguous, conflict-free). proj double-buffered in
// LDS, 16-k stages, 1 barrier/stage, register prefetch. Cross-wave (o,s,r)
// reduce through LDS at the end; no partial buffers, no extra kernels.
__global__ __launch_bounds__(512) void attn_fused(
    const float* __restrict__ msg, const int* __restrict__ adj,
    const float* __restrict__ proj, float* __restrict__ attn_out) {
  __shared__ float4 P[2][2][16 * 64];  // [k-half][buf][kk*64 + c4] = 64 KB

  const int t    = threadIdx.x;
  const int lane = t & 63;
  const int w    = t >> 6;     // 0..7
  const int hs   = w >> 2;     // k-half
  const int wl   = w & 3;      // wave within half
  const int th   = t & 255;    // thread id within half
  const int h    = lane >> 2;
  const int qc   = blockIdx.x;
  const int b    = blockIdx.y;
  const int qbase = qc * 16 + wl * 4;
  const int kb0  = hs * 256;

  const float* mp[4];
  const int*   ap[4];
#pragma unroll
  for (int qi = 0; qi < 4; ++qi) {
    const int q = qbase + qi;
    mp[qi] = msg + ((size_t)(b * NQ + q) * NKV) * Hh + h;
    ap[qi] = adj + (size_t)(b * NQ + q) * NKV;
  }
  const float4* pj = (const float4*)proj + (size_t)b * NKV * 64;

  // preload tile 0 -> buf 0
  float4 rl[4];
#pragma unroll
  for (int i = 0; i < 4; ++i) {
    const int flat = i * 256 + th;
    rl[i] = pj[(size_t)(kb0 + (flat >> 6)) * 64 + (flat & 63)];
  }
#pragma unroll
  for (int i = 0; i < 4; ++i) {
    const int flat = i * 256 + th;
    P[hs][0][(flat >> 6) * 64 + (flat & 63)] = rl[i];
  }
  __syncthreads();

  float4 o[4] = {};
  float s[4] = {}, r[4] = {};

  for (int tile = 0; tile < 16; ++tile) {
    const int cur = tile & 1;
    const int kb  = kb0 + tile * 16;
    if (tile < 15) {  // prefetch next proj tile into registers
      const int kn = kb + 16;
#pragma unroll
      for (int i = 0; i < 4; ++i) {
        const int flat = i * 256 + th;
        rl[i] = pj[(size_t)(kn + (flat >> 6)) * 64 + (flat & 63)];
      }
    }
#pragma unroll
    for (int g = 0; g < 4; ++g) {
      const int k = kb + g * 4;
      int a_[4][4];
      float m_[4][4];
#pragma unroll
      for (int qi = 0; qi < 4; ++qi) {
        *(int4*)a_[qi] = *(const int4*)(ap[qi] + k);
#pragma unroll
        for (int j = 0; j < 4; ++j)
          m_[qi][j] = mp[qi][(size_t)(k + j) * Hh];
      }
#pragma unroll
      for (int j = 0; j < 4; ++j) {
        const float4 p = P[hs][cur][(g * 4 + j) * 64 + lane];
#pragma unroll
        for (int qi = 0; qi < 4; ++qi) {
          const float e = (a_[qi][j] > 0) ? __expf(m_[qi][j]) : 0.0f;
          s[qi] += e;
          r[qi] = fmaf(e, e, r[qi]);
          o[qi].x = fmaf(e, p.x, o[qi].x);
          o[qi].y = fmaf(e, p.y, o[qi].y);
          o[qi].z = fmaf(e, p.z, o[qi].z);
          o[qi].w = fmaf(e, p.w, o[qi].w);
        }
      }
    }
    if (tile < 15) {  // write prefetched tile into other buffer
#pragma unroll
      for (int i = 0; i < 4; ++i) {
        const int flat = i * 256 + th;
        P[hs][cur ^ 1][(flat >> 6) * 64 + (flat & 63)] = rl[i];
      }
    }
    __syncthreads();
  }

  // cross-half reduce via LDS (stage buffers are dead now)
  float* redo = (float*)&P[0][0][0];          // [16][256]
  float* reds = redo + 16 * 256;              // [16][16]
  float* redr = reds + 256;                   // [16][16]
  const int dcol = lane << 2;

  if (hs == 1) {
#pragma unroll
    for (int qi = 0; qi < 4; ++qi) {
      const int qb = wl * 4 + qi;
      *(float4*)&redo[qb * 256 + dcol] = o[qi];
      if ((lane & 3) == 0) {
        reds[qb * 16 + h] = s[qi];
        redr[qb * 16 + h] = r[qi];
      }
    }
  }
  __syncthreads();
  if (hs == 0) {
#pragma unroll
    for (int qi = 0; qi < 4; ++qi) {
      const int qb = wl * 4 + qi;
      const float4 o1 = *(const float4*)&redo[qb * 256 + dcol];
      const float st = s[qi] + reds[qb * 16 + h];
      const float rt = r[qi] + redr[qb * 16 + h];
      const float wgt = sqrtf(rt) / (st * st);
      float4 u;
      u.x = (o[qi].x + o1.x) * wgt;
      u.y = (o[qi].y + o1.y) * wgt;
      u.z = (o[qi].z + o1.z) * wgt;
      u.w = (o[qi].w + o1.w) * wgt;
      const int q = qc * 16 + qb;
      *(float4*)(attn_out + (size_t)(b * NQ + q) * Dd + dcol) = u;
    }
  }
}

extern "C" void kernel_launch(void* const* d_in, const int* in_sizes, int n_in,
                              void* d_out, int out_size, void* d_ws, size_t ws_size,
                              hipStream_t stream) {
  const float* v_inv    = (const float*)d_in[0];
  const float* messages = (const float*)d_in[1];
  const int*   adj      = (const int*)d_in[2];
  const float* W_in     = (const float*)d_in[3];
  const float* b_in     = (const float*)d_in[4];
  const float* W_out    = (const float*)d_in[5];
  const float* b_out    = (const float*)d_in[6];
  float* out = (float*)d_out;

  float* proj = (float*)d_ws;                      // 4 MB [B,NKV,D]
  float* attn = proj + (size_t)8 * NKV * Dd;       // 4 MB [B,NQ,D]

  dim3 gg(64, 4);
  gemm_bias<<<gg, 256, 0, stream>>>(v_inv, W_in, b_in, proj);
  attn_fused<<<dim3(32, 8), 512, 0, stream>>>(messages, adj, proj, attn);
  gemm_bias<<<gg, 256, 0, stream>>>(attn, W_out, b_out, out);
}

// Round 6
// 260.273 us; speedup vs baseline: 1.4240x; 1.2465x over previous
//
#include <hip/hip_runtime.h>

constexpr int NQ = 512;
constexpr int NKV = 512;
constexpr int Hh = 16;
constexpr int Dd = 256;

// C = A @ W^T + bias. M=4096, N=256, K=256. BM=BN=64, BK=64.
__global__ __launch_bounds__(256) void gemm_bias(
    const float* __restrict__ A, const float* __restrict__ W,
    const float* __restrict__ bias, float* __restrict__ C) {
  __shared__ float As[64][68];
  __shared__ float Ws[64][68];
  const int t = threadIdx.x;
  const int tx = t & 15, ty = t >> 4;
  const int m0 = blockIdx.x * 64, n0 = blockIdx.y * 64;

  float acc[4][4] = {};

  for (int kb = 0; kb < 256; kb += 64) {
    __syncthreads();
#pragma unroll
    for (int i = 0; i < 4; ++i) {
      const int flat = i * 256 + t;
      const int r = flat >> 4, c4 = (flat & 15) << 2;
      const float4 av = *(const float4*)(A + (size_t)(m0 + r) * 256 + kb + c4);
      const float4 wv = *(const float4*)(W + (size_t)(n0 + r) * 256 + kb + c4);
      As[c4 + 0][r] = av.x; As[c4 + 1][r] = av.y;
      As[c4 + 2][r] = av.z; As[c4 + 3][r] = av.w;
      Ws[c4 + 0][r] = wv.x; Ws[c4 + 1][r] = wv.y;
      Ws[c4 + 2][r] = wv.z; Ws[c4 + 3][r] = wv.w;
    }
    __syncthreads();
#pragma unroll 16
    for (int k = 0; k < 64; ++k) {
      float a_[4], w_[4];
      *(float4*)a_ = *(const float4*)&As[k][ty << 2];
      *(float4*)w_ = *(const float4*)&Ws[k][tx << 2];
#pragma unroll
      for (int i = 0; i < 4; ++i)
#pragma unroll
        for (int j = 0; j < 4; ++j)
          acc[i][j] = fmaf(a_[i], w_[j], acc[i][j]);
    }
  }

  const float4 bv = *(const float4*)(bias + n0 + (tx << 2));
  const float bb[4] = {bv.x, bv.y, bv.z, bv.w};
#pragma unroll
  for (int i = 0; i < 4; ++i) {
    float4 cv;
    cv.x = acc[i][0] + bb[0]; cv.y = acc[i][1] + bb[1];
    cv.z = acc[i][2] + bb[2]; cv.w = acc[i][3] + bb[3];
    *(float4*)(C + (size_t)(m0 + (ty << 2) + i) * 256 + n0 + (tx << 2)) = cv;
  }
}

// Fused masked softmax + per-head aggregation + L2 rescale, two-phase.
// Block = (b, 8 q-rows), 512 thr = 8 waves = 4 k-quarters x 2 q-halves.
// 16 rounds; each round: phase1 stages proj (4 oct x 8 k rows) and E
// (e = mask*exp(msg), coalesced f4-over-h loads, in-register transpose,
// XOR-swizzled LDS store); phase2: e read as f4-over-k, p in registers,
// 4q x 16d register blocking. Epilogue: LDS tree-reduce over k-quarters.
__global__ __launch_bounds__(512, 4) void attn_fused(
    const float* __restrict__ msg, const int* __restrict__ adj,
    const float* __restrict__ proj, float* __restrict__ attn_out) {
  __shared__ float Psh[4][8][256];     // 32 KB: [oct][k][col]
  __shared__ float Esh[4][8][16][12];  // 24 KB: [oct][q][h^q][k(8 used)]

  const int t    = threadIdx.x;
  const int lane = t & 63;
  const int w    = t >> 6;      // wave 0..7
  const int oct  = w >> 1;      // k-quarter for phase2
  const int qh   = w & 1;       // q-half for phase2
  const int h    = lane >> 2;
  const int d4   = lane & 3;
  const int col  = lane << 2;   // = h*16 + d4*4
  const int q0   = blockIdx.x * 8;
  const int b    = blockIdx.y;

  // phase-1 decomposition
  const int p_h4  = t & 3;
  const int p_q   = (t >> 2) & 7;
  const int p_oct = (t >> 5) & 3;
  const int p_jp  = t >> 7;     // 0..3 (k-pair)

  const float* mrow = msg + ((size_t)(b * NQ + q0 + p_q) * NKV) * Hh + p_h4 * 4;
  const int*   arow = adj + (size_t)(b * NQ + q0 + p_q) * NKV;
  const float* pb   = proj + (size_t)b * NKV * Dd;

  float4 o[4] = {};
  float s[4] = {}, r[4] = {};

  for (int rd = 0; rd < 16; ++rd) {
    __syncthreads();
    // ---- phase 1a: stage proj[oct][0:8][0:256] for this round ----
#pragma unroll
    for (int i = 0; i < 4; ++i) {
      const int flat = i * 512 + t;
      const int row = flat >> 6;            // 0..31
      const int so = row >> 3, kk = row & 7;
      const int c4 = (flat & 63) << 2;
      *(float4*)&Psh[so][kk][c4] =
          *(const float4*)(pb + (size_t)(so * 128 + rd * 8 + kk) * Dd + c4);
    }
    // ---- phase 1b: E tile (mask*exp, transpose, swizzled store) ----
    {
      const int kg = p_oct * 128 + rd * 8 + p_jp * 2;
      const float4 mv0 = *(const float4*)(mrow + (size_t)kg * Hh);
      const float4 mv1 = *(const float4*)(mrow + (size_t)(kg + 1) * Hh);
      const int a0 = arow[kg], a1 = arow[kg + 1];
      float e0[4], e1[4];
      e0[0] = a0 > 0 ? __expf(mv0.x) : 0.f; e0[1] = a0 > 0 ? __expf(mv0.y) : 0.f;
      e0[2] = a0 > 0 ? __expf(mv0.z) : 0.f; e0[3] = a0 > 0 ? __expf(mv0.w) : 0.f;
      e1[0] = a1 > 0 ? __expf(mv1.x) : 0.f; e1[1] = a1 > 0 ? __expf(mv1.y) : 0.f;
      e1[2] = a1 > 0 ? __expf(mv1.z) : 0.f; e1[3] = a1 > 0 ? __expf(mv1.w) : 0.f;
#pragma unroll
      for (int i = 0; i < 4; ++i) {
        const int h2 = (p_h4 * 4 + i) ^ p_q;  // XOR swizzle
        *(float2*)&Esh[p_oct][p_q][h2][p_jp * 2] = make_float2(e0[i], e1[i]);
      }
    }
    __syncthreads();
    // ---- phase 2: accumulate over this round's 8 k of wave's quarter ----
#pragma unroll
    for (int kh = 0; kh < 2; ++kh) {
      float4 p[4];
#pragma unroll
      for (int j = 0; j < 4; ++j)
        p[j] = *(const float4*)&Psh[oct][kh * 4 + j][col];
#pragma unroll
      for (int qi = 0; qi < 4; ++qi) {
        const int ql = qh * 4 + qi;
        const float4 e4 = *(const float4*)&Esh[oct][ql][h ^ ql][kh * 4];
        s[qi] += e4.x + e4.y + e4.z + e4.w;
        r[qi] = fmaf(e4.x, e4.x, fmaf(e4.y, e4.y,
                fmaf(e4.z, e4.z, fmaf(e4.w, e4.w, r[qi]))));
        o[qi].x = fmaf(e4.x, p[0].x, o[qi].x);
        o[qi].y = fmaf(e4.x, p[0].y, o[qi].y);
        o[qi].z = fmaf(e4.x, p[0].z, o[qi].z);
        o[qi].w = fmaf(e4.x, p[0].w, o[qi].w);
        o[qi].x = fmaf(e4.y, p[1].x, o[qi].x);
        o[qi].y = fmaf(e4.y, p[1].y, o[qi].y);
        o[qi].z = fmaf(e4.y, p[1].z, o[qi].z);
        o[qi].w = fmaf(e4.y, p[1].w, o[qi].w);
        o[qi].x = fmaf(e4.z, p[2].x, o[qi].x);
        o[qi].y = fmaf(e4.z, p[2].y, o[qi].y);
        o[qi].z = fmaf(e4.z, p[2].z, o[qi].z);
        o[qi].w = fmaf(e4.z, p[2].w, o[qi].w);
        o[qi].x = fmaf(e4.w, p[3].x, o[qi].x);
        o[qi].y = fmaf(e4.w, p[3].y, o[qi].y);
        o[qi].z = fmaf(e4.w, p[3].z, o[qi].z);
        o[qi].w = fmaf(e4.w, p[3].w, o[qi].w);
      }
    }
  }

  // ---- epilogue: tree-reduce partial (o,s,r) over the 4 k-quarters ----
  float4* Ro = (float4*)&Psh[0][0][0];  // 16 KB used
  float*  Rs = &Esh[0][0][0][0];        // 256 floats
  float*  Rr = Rs + 256;                // 256 floats

  __syncthreads();
  if (w >= 4) {  // oct 2,3 write regions 0..3
    const int reg = w - 4;
#pragma unroll
    for (int qi = 0; qi < 4; ++qi) {
      Ro[(reg * 4 + qi) * 64 + lane] = o[qi];
      if (d4 == 0) {
        Rs[(reg * 4 + qi) * 16 + h] = s[qi];
        Rr[(reg * 4 + qi) * 16 + h] = r[qi];
      }
    }
  }
  __syncthreads();
  if (w < 4) {
#pragma unroll
    for (int qi = 0; qi < 4; ++qi) {
      const float4 v = Ro[(w * 4 + qi) * 64 + lane];
      o[qi].x += v.x; o[qi].y += v.y; o[qi].z += v.z; o[qi].w += v.w;
      s[qi] += Rs[(w * 4 + qi) * 16 + h];
      r[qi] += Rr[(w * 4 + qi) * 16 + h];
    }
  }
  __syncthreads();
  if (w == 2 || w == 3) {  // oct 1 writes regions 0,1
    const int reg = w - 2;
#pragma unroll
    for (int qi = 0; qi < 4; ++qi) {
      Ro[(reg * 4 + qi) * 64 + lane] = o[qi];
      if (d4 == 0) {
        Rs[(reg * 4 + qi) * 16 + h] = s[qi];
        Rr[(reg * 4 + qi) * 16 + h] = r[qi];
      }
    }
  }
  __syncthreads();
  if (w < 2) {
#pragma unroll
    for (int qi = 0; qi < 4; ++qi) {
      const float4 v = Ro[(w * 4 + qi) * 64 + lane];
      o[qi].x += v.x; o[qi].y += v.y; o[qi].z += v.z; o[qi].w += v.w;
      const float st = s[qi] + Rs[(w * 4 + qi) * 16 + h];
      const float rt = r[qi] + Rr[(w * 4 + qi) * 16 + h];
      const float wgt = sqrtf(rt) / (st * st);
      float4 u;
      u.x = o[qi].x * wgt; u.y = o[qi].y * wgt;
      u.z = o[qi].z * wgt; u.w = o[qi].w * wgt;
      const int q = q0 + w * 4 + qi;
      *(float4*)(attn_out + (size_t)(b * NQ + q) * Dd + col) = u;
    }
  }
}

extern "C" void kernel_launch(void* const* d_in, const int* in_sizes, int n_in,
                              void* d_out, int out_size, void* d_ws, size_t ws_size,
                              hipStream_t stream) {
  const float* v_inv    = (const float*)d_in[0];
  const float* messages = (const float*)d_in[1];
  const int*   adj      = (const int*)d_in[2];
  const float* W_in     = (const float*)d_in[3];
  const float* b_in     = (const float*)d_in[4];
  const float* W_out    = (const float*)d_in[5];
  const float* b_out    = (const float*)d_in[6];
  float* out = (float*)d_out;

  float* proj = (float*)d_ws;                      // 4 MB [B,NKV,D]
  float* attn = proj + (size_t)8 * NKV * Dd;       // 4 MB [B,NQ,D]

  dim3 gg(64, 4);
  gemm_bias<<<gg, 256, 0, stream>>>(v_inv, W_in, b_in, proj);
  attn_fused<<<dim3(64, 8), 512, 0, stream>>>(messages, adj, proj, attn);
  gemm_bias<<<gg, 256, 0, stream>>>(attn, W_out, b_out, out);
}